// Round 16
// baseline (339.312 us; speedup 1.0000x reference)
//
#include <hip/hip_runtime.h>
#include <math.h>

#define NROWS (512 * 512)
#define KCB   1024
#define DDIM  64
#define NQ    ((size_t)NROWS * DDIM)
#define RPW   32            // rows per wave
#define CMAX  8             // candidate cap per row
#define WAVES 8
#define BLKT  512
#define KPH   256           // codes per LDS phase (32 KB tile -> 3 blocks/CU)
#define NTPH  (KPH / 16)    // 16 k-tiles per phase

typedef __attribute__((ext_vector_type(8))) short bf16x8;
typedef __attribute__((ext_vector_type(4))) float f32x4;

__device__ __forceinline__ unsigned short f2bf(float x) {
    unsigned u = __float_as_uint(x);
    u = u + 0x7FFFu + ((u >> 16) & 1u);
    return (unsigned short)(u >> 16);
}
__device__ __forceinline__ unsigned fsort(float d) {   // monotonic f32 -> u32
    unsigned u = __float_as_uint(d);
    return (u & 0x80000000u) ? ~u : (u | 0x80000000u);
}

// ---------- K1: frozen wsq + w->bf16 + wmax ----------
__global__ __launch_bounds__(1024)
void prep_w(const float* __restrict__ w, float* __restrict__ bsq,
            unsigned short* __restrict__ wbf, float* __restrict__ wmaxp) {
    __shared__ float red[16];
    const int k = threadIdx.x;
    const float* row = w + (size_t)k * DDIM;
    float r[8];
#pragma unroll
    for (int j = 0; j < 8; ++j) r[j] = __fmul_rn(row[j], row[j]);
#pragma unroll
    for (int i = 8; i < DDIM; i += 8)
#pragma unroll
        for (int j = 0; j < 8; ++j)
            r[j] = __fadd_rn(r[j], __fmul_rn(row[i + j], row[i + j]));
    float b = __fadd_rn(__fadd_rn(__fadd_rn(r[0], r[1]), __fadd_rn(r[2], r[3])),
                        __fadd_rn(__fadd_rn(r[4], r[5]), __fadd_rn(r[6], r[7])));
    bsq[k] = b;
    unsigned* dst = (unsigned*)(wbf + (size_t)k * DDIM);
#pragma unroll
    for (int j = 0; j < 32; ++j)
        dst[j] = (unsigned)f2bf(row[2 * j]) | ((unsigned)f2bf(row[2 * j + 1]) << 16);
    float v = sqrtf(b) * 1.02f;
#pragma unroll
    for (int off = 1; off < 64; off <<= 1) v = fmaxf(v, __shfl_xor(v, off));
    if ((threadIdx.x & 63) == 0) red[threadIdx.x >> 6] = v;
    __syncthreads();
    if (threadIdx.x == 0) {
        float m = red[0];
#pragma unroll
        for (int j = 1; j < 16; ++j) m = fmaxf(m, red[j]);
        *wmaxp = m;
    }
}

// ---------- K3: single-pass LDS-staged scan, top-3 key chains, fused epilogue ----------
__global__ __launch_bounds__(BLKT, 4)
void vq_scan(const float* __restrict__ h, const float* __restrict__ w,
             const unsigned short* __restrict__ wbf, const float* __restrict__ bsq,
             const float* __restrict__ wmaxp, float* __restrict__ out) {
    // 32 KB swizzled codebook tile: row lr (0..255) x 8 float4 chunks;
    // chunk c stored at s4[lr*8 + (c ^ (lr&7))] (XOR involution, 16B granularity)
    __shared__ float4 s4[KPH * 8];
    __shared__ float sbsq[KPH];
    __shared__ int scnt[WAVES][RPW];
    __shared__ unsigned short sclist[WAVES][RPW][CMAX];
    __shared__ unsigned long long sbkey[WAVES][RPW];
    __shared__ int sflag[WAVES][RPW];

    const int tid = threadIdx.x;
    const int wv = tid >> 6, lane = tid & 63;
    const int l16 = lane & 15, lh = lane >> 4;
    const int rowbase = blockIdx.x * (WAVES * RPW) + wv * RPW;   // wave's 32 rows

    if (lane < RPW) {
        scnt[wv][lane] = 0;
        sflag[wv][lane] = 0;
        sbkey[wv][lane] = 0xFFFFFFFFFFFFFFFFULL;
    }

    // Af: frozen pairwise-8 (lane r computes row r)
    float af = 0.f;
    if (lane < RPW) {
        const float* row = h + (size_t)(rowbase + lane) * DDIM;
        float hr[DDIM];
#pragma unroll
        for (int i = 0; i < DDIM; i += 4) {
            float4 v = *reinterpret_cast<const float4*>(row + i);
            hr[i] = v.x; hr[i + 1] = v.y; hr[i + 2] = v.z; hr[i + 3] = v.w;
        }
        float s[8];
#pragma unroll
        for (int j = 0; j < 8; ++j) s[j] = __fmul_rn(hr[j], hr[j]);
#pragma unroll
        for (int i = 8; i < DDIM; i += 8)
#pragma unroll
            for (int j = 0; j < 8; ++j)
                s[j] = __fadd_rn(s[j], __fmul_rn(hr[i + j], hr[i + j]));
        af = __fadd_rn(__fadd_rn(__fadd_rn(s[0], s[1]), __fadd_rn(s[2], s[3])),
                       __fadd_rn(__fadd_rn(s[4], s[5]), __fadd_rn(s[6], s[7])));
    }

    // A-frags (h rows, bf16) — layout validated R10-R15
    bf16x8 afr[2][2];
#pragma unroll
    for (int mt = 0; mt < 2; ++mt) {
        const float* hrow = h + ((size_t)(rowbase + mt * 16 + l16)) * DDIM;
#pragma unroll
        for (int dh = 0; dh < 2; ++dh) {
            float4 a = *reinterpret_cast<const float4*>(hrow + dh * 32 + lh * 8);
            float4 bq = *reinterpret_cast<const float4*>(hrow + dh * 32 + lh * 8 + 4);
            union { bf16x8 v; unsigned short u[8]; } pk;
            pk.u[0] = f2bf(a.x); pk.u[1] = f2bf(a.y); pk.u[2] = f2bf(a.z); pk.u[3] = f2bf(a.w);
            pk.u[4] = f2bf(bq.x); pk.u[5] = f2bf(bq.y); pk.u[6] = f2bf(bq.z); pk.u[7] = f2bf(bq.w);
            afr[mt][dh] = pk.v;
        }
    }

    // per-lane constant swizzled chunk indices (lr&7 == l16&7 since nt*16 ≡ 0 mod 8)
    const int sw = l16 & 7;
    const int C0 = lh ^ sw;         // chunk for d0..31
    const int C1 = (4 + lh) ^ sw;   // chunk for d32..63

    // top-3 identity-carrying key chains: key = asfloat((asuint(val)&~0x3FF)|k)
    float key1[8], key2[8], key3[8];
#pragma unroll
    for (int j = 0; j < 8; ++j) { key1[j] = INFINITY; key2[j] = INFINITY; key3[j] = INFINITY; }

    const float4* g4all = reinterpret_cast<const float4*>(wbf);

    // ================== single pass: 4 staged phases ==================
#pragma unroll 1
    for (int ph = 0; ph < 4; ++ph) {
        const int k0 = ph * KPH;
        __syncthreads();   // protect previous phase readers before overwrite
        // stage: linear LDS write, inverse-permuted global read (rule-21 pair)
        const float4* g4 = g4all + (size_t)k0 * 8;
#pragma unroll
        for (int j = 0; j < 4; ++j) {
            int F = j * BLKT + tid;          // 0..2047 LDS float4 index
            int r = F >> 3, c = F & 7;
            s4[F] = g4[r * 8 + (c ^ (r & 7))];
        }
        if (tid < KPH) sbsq[tid] = bsq[k0 + tid];
        __syncthreads();

        // depth-2 register prefetch from LDS
        float4 pb0[2], pb1[2];
        float pbq[2];
#pragma unroll
        for (int q = 0; q < 2; ++q) {
            const int lr = q * 16 + l16;
            pb0[q] = s4[lr * 8 + C0];
            pb1[q] = s4[lr * 8 + C1];
            pbq[q] = sbsq[lr];
        }
#pragma unroll 4
        for (int nt = 0; nt < NTPH; ++nt) {
            const int s = nt & 1;
            float4 b0 = pb0[s], b1 = pb1[s];
            float bq = pbq[s];
            {
                const int ntn = (nt + 2 < NTPH) ? (nt + 2) : (NTPH - 1);
                const int lr = ntn * 16 + l16;
                pb0[s] = s4[lr * 8 + C0];
                pb1[s] = s4[lr * 8 + C1];
                pbq[s] = sbsq[lr];
            }
            bf16x8 bfr0 = *reinterpret_cast<const bf16x8*>(&b0);
            bf16x8 bfr1 = *reinterpret_cast<const bf16x8*>(&b1);
            const unsigned kk = (unsigned)(k0 + nt * 16 + l16);   // 10 bits
#pragma unroll
            for (int mt = 0; mt < 2; ++mt) {
                f32x4 acc = {0.f, 0.f, 0.f, 0.f};
                acc = __builtin_amdgcn_mfma_f32_16x16x32_bf16(afr[mt][0], bfr0, acc, 0, 0, 0);
                acc = __builtin_amdgcn_mfma_f32_16x16x32_bf16(afr[mt][1], bfr1, acc, 0, 0, 0);
#pragma unroll
                for (int i = 0; i < 4; ++i) {
                    const int j = mt * 4 + i;
                    float val = bq - (acc[i] + acc[i]);
                    float key = __uint_as_float((__float_as_uint(val) & 0xFFFFFC00u) | kk);
                    // 3-deep sorted insert (branchless network)
                    float m1 = fminf(key1[j], key);
                    float M1 = fmaxf(key1[j], key);
                    float m2 = fminf(key2[j], M1);
                    float M2 = fmaxf(key2[j], M1);
                    float m3 = fminf(key3[j], M2);
                    key1[j] = m1; key2[j] = m2; key3[j] = m3;
                }
            }
        }
    }

    // global row-min: butterfly key1 over the 16 l16-lanes
    float gmin[8];
#pragma unroll
    for (int j = 0; j < 8; ++j) gmin[j] = key1[j];
#pragma unroll
    for (int off = 1; off < 16; off <<= 1)
#pragma unroll
        for (int j = 0; j < 8; ++j) gmin[j] = fminf(gmin[j], __shfl_xor(gmin[j], off));

    // thresholds (validated margin formula; gmin ≈ pmin within ~4e-6, absorbed)
    const float wmaxv = *wmaxp;
    float tr[8];
#pragma unroll
    for (int mt = 0; mt < 2; ++mt)
#pragma unroll
        for (int i = 0; i < 4; ++i) {
            float Afr = __shfl(af, mt * 16 + lh * 4 + i);
            tr[mt * 4 + i] = gmin[mt * 4 + i] + sqrtf(Afr) * 1.001f * wmaxv * 0.03125f + 1e-3f;
        }

    // candidate push from the chains; key3 ≤ thr ⇒ possible hidden 4th ⇒ flag row
#pragma unroll
    for (int j = 0; j < 8; ++j) {
        const int row = (j >> 2) * 16 + lh * 4 + (j & 3);
        if (key1[j] <= tr[j]) {
            int slot = atomicAdd(&scnt[wv][row], 1);
            if (slot < CMAX) sclist[wv][row][slot] = (unsigned short)(__float_as_uint(key1[j]) & 1023u);
        }
        if (key2[j] <= tr[j]) {
            int slot = atomicAdd(&scnt[wv][row], 1);
            if (slot < CMAX) sclist[wv][row][slot] = (unsigned short)(__float_as_uint(key2[j]) & 1023u);
        }
        if (key3[j] <= tr[j]) {
            int slot = atomicAdd(&scnt[wv][row], 1);
            if (slot < CMAX) sclist[wv][row][slot] = (unsigned short)(__float_as_uint(key3[j]) & 1023u);
            sflag[wv][row] = 1;   // same-value concurrent LDS stores: benign
        }
    }
    __builtin_amdgcn_wave_barrier();

    // ---- rescore: 2 lanes/row, exact frozen chain, (d,k) atomicMin key ----
    {
        const int row = lane >> 1;
        const int s0 = lane & 1;
        const float Afr = __shfl(af, row);
        const int cnt = scnt[wv][row];
        if (cnt <= CMAX && s0 < cnt) {
            const size_t ng = (size_t)rowbase + row;
            const float* hrow = h + ng * DDIM;
            float hreg[DDIM];
#pragma unroll
            for (int i = 0; i < DDIM; i += 4) {
                float4 v = *reinterpret_cast<const float4*>(hrow + i);
                hreg[i] = v.x; hreg[i + 1] = v.y; hreg[i + 2] = v.z; hreg[i + 3] = v.w;
            }
            for (int slot = s0; slot < cnt; slot += 2) {
                int k = sclist[wv][row][slot];
                const float* wr = w + (size_t)k * DDIM;
                float acc = 0.f;
#pragma unroll
                for (int i = 0; i < DDIM; i += 4) {
                    float4 x = *reinterpret_cast<const float4*>(wr + i);
                    acc = fmaf(hreg[i + 0], x.x, acc);
                    acc = fmaf(hreg[i + 1], x.y, acc);
                    acc = fmaf(hreg[i + 2], x.z, acc);
                    acc = fmaf(hreg[i + 3], x.w, acc);
                }
                float d = __fsub_rn(__fadd_rn(Afr, bsq[k]), __fadd_rn(acc, acc));
                unsigned long long key = ((unsigned long long)fsort(d) << 32) | (unsigned)k;
                atomicMin(&sbkey[wv][row], key);
            }
        }
    }
    // fallback: exact full scan for overflowed/flagged rows (rare)
#pragma unroll 1
    for (int r = 0; r < RPW; ++r) {
        const float Afr = __shfl(af, r);
        if (scnt[wv][r] > CMAX || sflag[wv][r]) {
            const size_t ng = (size_t)rowbase + r;
            const float* hrow = h + ng * DDIM;
            float hreg[DDIM];
#pragma unroll
            for (int i = 0; i < DDIM; i += 4) {
                float4 v = *reinterpret_cast<const float4*>(hrow + i);
                hreg[i] = v.x; hreg[i + 1] = v.y; hreg[i + 2] = v.z; hreg[i + 3] = v.w;
            }
            for (int k = lane; k < KCB; k += 64) {
                const float* wr = w + (size_t)k * DDIM;
                float acc = 0.f;
#pragma unroll
                for (int i = 0; i < DDIM; i += 4) {
                    float4 x = *reinterpret_cast<const float4*>(wr + i);
                    acc = fmaf(hreg[i + 0], x.x, acc);
                    acc = fmaf(hreg[i + 1], x.y, acc);
                    acc = fmaf(hreg[i + 2], x.z, acc);
                    acc = fmaf(hreg[i + 3], x.w, acc);
                }
                float d = __fsub_rn(__fadd_rn(Afr, bsq[k]), __fadd_rn(acc, acc));
                unsigned long long key = ((unsigned long long)fsort(d) << 32) | (unsigned)k;
                atomicMin(&sbkey[wv][r], key);
            }
        }
    }
    __builtin_amdgcn_wave_barrier();

    // ---- fused outputs (per wave) — frozen R13-R15 ----
    if (lane < RPW)
        out[NQ + rowbase + lane] = (float)(unsigned)(sbkey[wv][lane] & 0xFFFFFFFFu);

#pragma unroll
    for (int q = 0; q < 8; ++q) {
        const int idx = q * 64 + lane;
        const int row = idx >> 4, c4 = idx & 15;
        const int bk = (int)(unsigned)(sbkey[wv][row] & 0xFFFFFFFFu);
        const size_t ng = (size_t)rowbase + row;
        float4 hq = *reinterpret_cast<const float4*>(h + ng * DDIM + 4 * c4);
        float4 wq = *reinterpret_cast<const float4*>(w + (size_t)bk * DDIM + 4 * c4);
        float4 o;
        o.x = __fadd_rn(hq.x, __fsub_rn(wq.x, hq.x));
        o.y = __fadd_rn(hq.y, __fsub_rn(wq.y, hq.y));
        o.z = __fadd_rn(hq.z, __fsub_rn(wq.z, hq.z));
        o.w = __fadd_rn(hq.w, __fsub_rn(wq.w, hq.w));
        *reinterpret_cast<float4*>(out + ng * DDIM + 4 * c4) = o;
    }

    if (lane < RPW) {
        const int bk = (int)(unsigned)(sbkey[wv][lane] & 0xFFFFFFFFu);
        const size_t ng = (size_t)rowbase + lane;
        const float* hrow = h + ng * DDIM;
        const float* qrow = w + (size_t)bk * DDIM;
        float hr[DDIM];
#pragma unroll
        for (int i = 0; i < DDIM; i += 4) {
            float4 v = *reinterpret_cast<const float4*>(hrow + i);
            hr[i] = v.x; hr[i + 1] = v.y; hr[i + 2] = v.z; hr[i + 3] = v.w;
        }
        float r2[8];
#pragma unroll
        for (int c = 0; c < 8; ++c) {
            float4 qa = *reinterpret_cast<const float4*>(qrow + 8 * c);
            float4 qb = *reinterpret_cast<const float4*>(qrow + 8 * c + 4);
            float d0 = __fsub_rn(qa.x, hr[8 * c + 0]);
            float d1 = __fsub_rn(qa.y, hr[8 * c + 1]);
            float d2 = __fsub_rn(qa.z, hr[8 * c + 2]);
            float d3 = __fsub_rn(qa.w, hr[8 * c + 3]);
            float d4 = __fsub_rn(qb.x, hr[8 * c + 4]);
            float d5 = __fsub_rn(qb.y, hr[8 * c + 5]);
            float d6 = __fsub_rn(qb.z, hr[8 * c + 6]);
            float d7 = __fsub_rn(qb.w, hr[8 * c + 7]);
            if (c == 0) {
                r2[0] = __fmul_rn(d0, d0); r2[1] = __fmul_rn(d1, d1);
                r2[2] = __fmul_rn(d2, d2); r2[3] = __fmul_rn(d3, d3);
                r2[4] = __fmul_rn(d4, d4); r2[5] = __fmul_rn(d5, d5);
                r2[6] = __fmul_rn(d6, d6); r2[7] = __fmul_rn(d7, d7);
            } else {
                r2[0] = __fadd_rn(r2[0], __fmul_rn(d0, d0));
                r2[1] = __fadd_rn(r2[1], __fmul_rn(d1, d1));
                r2[2] = __fadd_rn(r2[2], __fmul_rn(d2, d2));
                r2[3] = __fadd_rn(r2[3], __fmul_rn(d3, d3));
                r2[4] = __fadd_rn(r2[4], __fmul_rn(d4, d4));
                r2[5] = __fadd_rn(r2[5], __fmul_rn(d5, d5));
                r2[6] = __fadd_rn(r2[6], __fmul_rn(d6, d6));
                r2[7] = __fadd_rn(r2[7], __fmul_rn(d7, d7));
            }
        }
        float S = __fadd_rn(__fadd_rn(__fadd_rn(r2[0], r2[1]), __fadd_rn(r2[2], r2[3])),
                            __fadd_rn(__fadd_rn(r2[4], r2[5]), __fadd_rn(r2[6], r2[7])));
        float m = __fmul_rn(S, 0.015625f);
        out[NQ + NROWS + ng] = __fadd_rn(__fmul_rn(m, 0.1f), __fmul_rn(m, 0.2f));
    }
}

extern "C" void kernel_launch(void* const* d_in, const int* in_sizes, int n_in,
                              void* d_out, int out_size, void* d_ws, size_t ws_size,
                              hipStream_t stream) {
    (void)in_sizes; (void)n_in; (void)out_size; (void)ws_size;
    const float* h = (const float*)d_in[0];
    const float* w = (const float*)d_in[1];
    float* out = (float*)d_out;

    char* ws = (char*)d_ws;
    float* bsq = (float*)ws;                               // 4 KB
    float* wmaxp = (float*)(ws + 4096);                    // 16 B
    unsigned short* wbf = (unsigned short*)(ws + 8192);    // 128 KB

    prep_w<<<1, 1024, 0, stream>>>(w, bsq, wbf, wmaxp);
    vq_scan<<<NROWS / (WAVES * RPW), BLKT, 0, stream>>>(h, w, wbf, bsq, wmaxp, out);
}

// Round 17
// 333.144 us; speedup vs baseline: 1.0185x; 1.0185x over previous
//
#include <hip/hip_runtime.h>
#include <math.h>

#define NROWS (512 * 512)
#define KCB   1024
#define DDIM  64
#define NQ    ((size_t)NROWS * DDIM)
#define RPW   32            // rows per wave
#define CMAX  8             // candidate cap per row
#define WAVES 8
#define BLKT  512
#define KPH   512           // codes per LDS phase (R15's validated ratio)
#define NTPH  (KPH / 16)    // 32 k-tiles per phase

typedef __attribute__((ext_vector_type(8))) short bf16x8;
typedef __attribute__((ext_vector_type(4))) float f32x4;

__device__ __forceinline__ unsigned short f2bf(float x) {
    unsigned u = __float_as_uint(x);
    u = u + 0x7FFFu + ((u >> 16) & 1u);
    return (unsigned short)(u >> 16);
}
__device__ __forceinline__ unsigned fsort(float d) {   // monotonic f32 -> u32
    unsigned u = __float_as_uint(d);
    return (u & 0x80000000u) ? ~u : (u | 0x80000000u);
}

// ---------- K1: frozen wsq + w->bf16 + wmax ----------
__global__ __launch_bounds__(1024)
void prep_w(const float* __restrict__ w, float* __restrict__ bsq,
            unsigned short* __restrict__ wbf, float* __restrict__ wmaxp) {
    __shared__ float red[16];
    const int k = threadIdx.x;
    const float* row = w + (size_t)k * DDIM;
    float r[8];
#pragma unroll
    for (int j = 0; j < 8; ++j) r[j] = __fmul_rn(row[j], row[j]);
#pragma unroll
    for (int i = 8; i < DDIM; i += 8)
#pragma unroll
        for (int j = 0; j < 8; ++j)
            r[j] = __fadd_rn(r[j], __fmul_rn(row[i + j], row[i + j]));
    float b = __fadd_rn(__fadd_rn(__fadd_rn(r[0], r[1]), __fadd_rn(r[2], r[3])),
                        __fadd_rn(__fadd_rn(r[4], r[5]), __fadd_rn(r[6], r[7])));
    bsq[k] = b;
    unsigned* dst = (unsigned*)(wbf + (size_t)k * DDIM);
#pragma unroll
    for (int j = 0; j < 32; ++j)
        dst[j] = (unsigned)f2bf(row[2 * j]) | ((unsigned)f2bf(row[2 * j + 1]) << 16);
    float v = sqrtf(b) * 1.02f;
#pragma unroll
    for (int off = 1; off < 64; off <<= 1) v = fmaxf(v, __shfl_xor(v, off));
    if ((threadIdx.x & 63) == 0) red[threadIdx.x >> 6] = v;
    __syncthreads();
    if (threadIdx.x == 0) {
        float m = red[0];
#pragma unroll
        for (int j = 1; j < 16; ++j) m = fmaxf(m, red[j]);
        *wmaxp = m;
    }
}

// ---------- K3: single-pass scan, KPH=512, top-3 key chains, fused epilogue ----------
__global__ __launch_bounds__(BLKT, 2)
void vq_scan(const float* __restrict__ h, const float* __restrict__ w,
             const unsigned short* __restrict__ wbf, const float* __restrict__ bsq,
             const float* __restrict__ wmaxp, float* __restrict__ out) {
    // 64 KB swizzled codebook tile: row lr (0..511) x 8 float4 chunks;
    // chunk c stored at s4[lr*8 + (c ^ (lr&7))] (XOR involution, 16B granularity)
    __shared__ float4 s4[KPH * 8];
    __shared__ float sbsq[KPH];
    __shared__ int scnt[WAVES][RPW];
    __shared__ unsigned short sclist[WAVES][RPW][CMAX];
    __shared__ unsigned long long sbkey[WAVES][RPW];
    __shared__ int sflag[WAVES][RPW];

    const int tid = threadIdx.x;
    const int wv = tid >> 6, lane = tid & 63;
    const int l16 = lane & 15, lh = lane >> 4;
    const int rowbase = blockIdx.x * (WAVES * RPW) + wv * RPW;   // wave's 32 rows

    if (lane < RPW) {
        scnt[wv][lane] = 0;
        sflag[wv][lane] = 0;
        sbkey[wv][lane] = 0xFFFFFFFFFFFFFFFFULL;
    }

    // Af: frozen pairwise-8 (lane r computes row r)
    float af = 0.f;
    if (lane < RPW) {
        const float* row = h + (size_t)(rowbase + lane) * DDIM;
        float hr[DDIM];
#pragma unroll
        for (int i = 0; i < DDIM; i += 4) {
            float4 v = *reinterpret_cast<const float4*>(row + i);
            hr[i] = v.x; hr[i + 1] = v.y; hr[i + 2] = v.z; hr[i + 3] = v.w;
        }
        float s[8];
#pragma unroll
        for (int j = 0; j < 8; ++j) s[j] = __fmul_rn(hr[j], hr[j]);
#pragma unroll
        for (int i = 8; i < DDIM; i += 8)
#pragma unroll
            for (int j = 0; j < 8; ++j)
                s[j] = __fadd_rn(s[j], __fmul_rn(hr[i + j], hr[i + j]));
        af = __fadd_rn(__fadd_rn(__fadd_rn(s[0], s[1]), __fadd_rn(s[2], s[3])),
                       __fadd_rn(__fadd_rn(s[4], s[5]), __fadd_rn(s[6], s[7])));
    }

    // A-frags (h rows, bf16) — layout validated R10-R16
    bf16x8 afr[2][2];
#pragma unroll
    for (int mt = 0; mt < 2; ++mt) {
        const float* hrow = h + ((size_t)(rowbase + mt * 16 + l16)) * DDIM;
#pragma unroll
        for (int dh = 0; dh < 2; ++dh) {
            float4 a = *reinterpret_cast<const float4*>(hrow + dh * 32 + lh * 8);
            float4 bq = *reinterpret_cast<const float4*>(hrow + dh * 32 + lh * 8 + 4);
            union { bf16x8 v; unsigned short u[8]; } pk;
            pk.u[0] = f2bf(a.x); pk.u[1] = f2bf(a.y); pk.u[2] = f2bf(a.z); pk.u[3] = f2bf(a.w);
            pk.u[4] = f2bf(bq.x); pk.u[5] = f2bf(bq.y); pk.u[6] = f2bf(bq.z); pk.u[7] = f2bf(bq.w);
            afr[mt][dh] = pk.v;
        }
    }

    // per-lane constant swizzled chunk indices (lr&7 == l16&7 since nt*16 ≡ 0 mod 8)
    const int sw = l16 & 7;
    const int C0 = lh ^ sw;         // chunk for d0..31
    const int C1 = (4 + lh) ^ sw;   // chunk for d32..63

    // top-3 identity-carrying key chains: key = asfloat((asuint(val)&~0x3FF)|k)
    // (vals |.|<~0.13 ⇒ stuffing perturbs ≤~1.5e-5 ≪ margin slack; validated R16)
    float key1[8], key2[8], key3[8];
#pragma unroll
    for (int j = 0; j < 8; ++j) { key1[j] = INFINITY; key2[j] = INFINITY; key3[j] = INFINITY; }

    const float4* g4all = reinterpret_cast<const float4*>(wbf);

    // ================== single pass: 2 staged phases (R15 ratio) ==================
#pragma unroll 1
    for (int ph = 0; ph < 2; ++ph) {
        const int k0 = ph * KPH;
        __syncthreads();   // protect previous phase readers before overwrite
        // stage: linear LDS write, inverse-permuted global read (rule-21 pair)
        const float4* g4 = g4all + (size_t)k0 * 8;
#pragma unroll
        for (int j = 0; j < 8; ++j) {
            int F = j * BLKT + tid;          // 0..4095 LDS float4 index
            int r = F >> 3, c = F & 7;
            s4[F] = g4[r * 8 + (c ^ (r & 7))];
        }
        sbsq[tid] = bsq[k0 + tid];
        __syncthreads();

        // depth-2 register prefetch from LDS
        float4 pb0[2], pb1[2];
        float pbq[2];
#pragma unroll
        for (int q = 0; q < 2; ++q) {
            const int lr = q * 16 + l16;
            pb0[q] = s4[lr * 8 + C0];
            pb1[q] = s4[lr * 8 + C1];
            pbq[q] = sbsq[lr];
        }
#pragma unroll 4
        for (int nt = 0; nt < NTPH; ++nt) {
            const int s = nt & 1;
            float4 b0 = pb0[s], b1 = pb1[s];
            float bq = pbq[s];
            {
                const int ntn = (nt + 2 < NTPH) ? (nt + 2) : (NTPH - 1);
                const int lr = ntn * 16 + l16;
                pb0[s] = s4[lr * 8 + C0];
                pb1[s] = s4[lr * 8 + C1];
                pbq[s] = sbsq[lr];
            }
            bf16x8 bfr0 = *reinterpret_cast<const bf16x8*>(&b0);
            bf16x8 bfr1 = *reinterpret_cast<const bf16x8*>(&b1);
            const unsigned kk = (unsigned)(k0 + nt * 16 + l16);   // 10 bits
#pragma unroll
            for (int mt = 0; mt < 2; ++mt) {
                f32x4 acc = {0.f, 0.f, 0.f, 0.f};
                acc = __builtin_amdgcn_mfma_f32_16x16x32_bf16(afr[mt][0], bfr0, acc, 0, 0, 0);
                acc = __builtin_amdgcn_mfma_f32_16x16x32_bf16(afr[mt][1], bfr1, acc, 0, 0, 0);
#pragma unroll
                for (int i = 0; i < 4; ++i) {
                    const int j = mt * 4 + i;
                    float val = bq - (acc[i] + acc[i]);
                    float key = __uint_as_float((__float_as_uint(val) & 0xFFFFFC00u) | kk);
                    // 3-deep sorted insert (branchless network)
                    float m1 = fminf(key1[j], key);
                    float M1 = fmaxf(key1[j], key);
                    float m2 = fminf(key2[j], M1);
                    float M2 = fmaxf(key2[j], M1);
                    float m3 = fminf(key3[j], M2);
                    key1[j] = m1; key2[j] = m2; key3[j] = m3;
                }
            }
        }
    }

    // global row-min: butterfly key1 over the 16 l16-lanes
    float gmin[8];
#pragma unroll
    for (int j = 0; j < 8; ++j) gmin[j] = key1[j];
#pragma unroll
    for (int off = 1; off < 16; off <<= 1)
#pragma unroll
        for (int j = 0; j < 8; ++j) gmin[j] = fminf(gmin[j], __shfl_xor(gmin[j], off));

    // thresholds (validated margin formula)
    const float wmaxv = *wmaxp;
    float tr[8];
#pragma unroll
    for (int mt = 0; mt < 2; ++mt)
#pragma unroll
        for (int i = 0; i < 4; ++i) {
            float Afr = __shfl(af, mt * 16 + lh * 4 + i);
            tr[mt * 4 + i] = gmin[mt * 4 + i] + sqrtf(Afr) * 1.001f * wmaxv * 0.03125f + 1e-3f;
        }

    // candidate push from the chains; key3 ≤ thr ⇒ possible hidden 4th ⇒ flag row
#pragma unroll
    for (int j = 0; j < 8; ++j) {
        const int row = (j >> 2) * 16 + lh * 4 + (j & 3);
        if (key1[j] <= tr[j]) {
            int slot = atomicAdd(&scnt[wv][row], 1);
            if (slot < CMAX) sclist[wv][row][slot] = (unsigned short)(__float_as_uint(key1[j]) & 1023u);
        }
        if (key2[j] <= tr[j]) {
            int slot = atomicAdd(&scnt[wv][row], 1);
            if (slot < CMAX) sclist[wv][row][slot] = (unsigned short)(__float_as_uint(key2[j]) & 1023u);
        }
        if (key3[j] <= tr[j]) {
            int slot = atomicAdd(&scnt[wv][row], 1);
            if (slot < CMAX) sclist[wv][row][slot] = (unsigned short)(__float_as_uint(key3[j]) & 1023u);
            sflag[wv][row] = 1;   // same-value concurrent LDS stores: benign
        }
    }
    __builtin_amdgcn_wave_barrier();

    // ---- rescore: 2 lanes/row, exact frozen chain, (d,k) atomicMin key ----
    {
        const int row = lane >> 1;
        const int s0 = lane & 1;
        const float Afr = __shfl(af, row);
        const int cnt = scnt[wv][row];
        if (cnt <= CMAX && s0 < cnt) {
            const size_t ng = (size_t)rowbase + row;
            const float* hrow = h + ng * DDIM;
            float hreg[DDIM];
#pragma unroll
            for (int i = 0; i < DDIM; i += 4) {
                float4 v = *reinterpret_cast<const float4*>(hrow + i);
                hreg[i] = v.x; hreg[i + 1] = v.y; hreg[i + 2] = v.z; hreg[i + 3] = v.w;
            }
            for (int slot = s0; slot < cnt; slot += 2) {
                int k = sclist[wv][row][slot];
                const float* wr = w + (size_t)k * DDIM;
                float acc = 0.f;
#pragma unroll
                for (int i = 0; i < DDIM; i += 4) {
                    float4 x = *reinterpret_cast<const float4*>(wr + i);
                    acc = fmaf(hreg[i + 0], x.x, acc);
                    acc = fmaf(hreg[i + 1], x.y, acc);
                    acc = fmaf(hreg[i + 2], x.z, acc);
                    acc = fmaf(hreg[i + 3], x.w, acc);
                }
                float d = __fsub_rn(__fadd_rn(Afr, bsq[k]), __fadd_rn(acc, acc));
                unsigned long long key = ((unsigned long long)fsort(d) << 32) | (unsigned)k;
                atomicMin(&sbkey[wv][row], key);
            }
        }
    }
    // fallback: exact full scan for overflowed/flagged rows (rare)
#pragma unroll 1
    for (int r = 0; r < RPW; ++r) {
        const float Afr = __shfl(af, r);
        if (scnt[wv][r] > CMAX || sflag[wv][r]) {
            const size_t ng = (size_t)rowbase + r;
            const float* hrow = h + ng * DDIM;
            float hreg[DDIM];
#pragma unroll
            for (int i = 0; i < DDIM; i += 4) {
                float4 v = *reinterpret_cast<const float4*>(hrow + i);
                hreg[i] = v.x; hreg[i + 1] = v.y; hreg[i + 2] = v.z; hreg[i + 3] = v.w;
            }
            for (int k = lane; k < KCB; k += 64) {
                const float* wr = w + (size_t)k * DDIM;
                float acc = 0.f;
#pragma unroll
                for (int i = 0; i < DDIM; i += 4) {
                    float4 x = *reinterpret_cast<const float4*>(wr + i);
                    acc = fmaf(hreg[i + 0], x.x, acc);
                    acc = fmaf(hreg[i + 1], x.y, acc);
                    acc = fmaf(hreg[i + 2], x.z, acc);
                    acc = fmaf(hreg[i + 3], x.w, acc);
                }
                float d = __fsub_rn(__fadd_rn(Afr, bsq[k]), __fadd_rn(acc, acc));
                unsigned long long key = ((unsigned long long)fsort(d) << 32) | (unsigned)k;
                atomicMin(&sbkey[wv][r], key);
            }
        }
    }
    __builtin_amdgcn_wave_barrier();

    // ---- fused outputs (per wave) — frozen R13-R16 ----
    if (lane < RPW)
        out[NQ + rowbase + lane] = (float)(unsigned)(sbkey[wv][lane] & 0xFFFFFFFFu);

#pragma unroll
    for (int q = 0; q < 8; ++q) {
        const int idx = q * 64 + lane;
        const int row = idx >> 4, c4 = idx & 15;
        const int bk = (int)(unsigned)(sbkey[wv][row] & 0xFFFFFFFFu);
        const size_t ng = (size_t)rowbase + row;
        float4 hq = *reinterpret_cast<const float4*>(h + ng * DDIM + 4 * c4);
        float4 wq = *reinterpret_cast<const float4*>(w + (size_t)bk * DDIM + 4 * c4);
        float4 o;
        o.x = __fadd_rn(hq.x, __fsub_rn(wq.x, hq.x));
        o.y = __fadd_rn(hq.y, __fsub_rn(wq.y, hq.y));
        o.z = __fadd_rn(hq.z, __fsub_rn(wq.z, hq.z));
        o.w = __fadd_rn(hq.w, __fsub_rn(wq.w, hq.w));
        *reinterpret_cast<float4*>(out + ng * DDIM + 4 * c4) = o;
    }

    if (lane < RPW) {
        const int bk = (int)(unsigned)(sbkey[wv][lane] & 0xFFFFFFFFu);
        const size_t ng = (size_t)rowbase + lane;
        const float* hrow = h + ng * DDIM;
        const float* qrow = w + (size_t)bk * DDIM;
        float hr[DDIM];
#pragma unroll
        for (int i = 0; i < DDIM; i += 4) {
            float4 v = *reinterpret_cast<const float4*>(hrow + i);
            hr[i] = v.x; hr[i + 1] = v.y; hr[i + 2] = v.z; hr[i + 3] = v.w;
        }
        float r2[8];
#pragma unroll
        for (int c = 0; c < 8; ++c) {
            float4 qa = *reinterpret_cast<const float4*>(qrow + 8 * c);
            float4 qb = *reinterpret_cast<const float4*>(qrow + 8 * c + 4);
            float d0 = __fsub_rn(qa.x, hr[8 * c + 0]);
            float d1 = __fsub_rn(qa.y, hr[8 * c + 1]);
            float d2 = __fsub_rn(qa.z, hr[8 * c + 2]);
            float d3 = __fsub_rn(qa.w, hr[8 * c + 3]);
            float d4 = __fsub_rn(qb.x, hr[8 * c + 4]);
            float d5 = __fsub_rn(qb.y, hr[8 * c + 5]);
            float d6 = __fsub_rn(qb.z, hr[8 * c + 6]);
            float d7 = __fsub_rn(qb.w, hr[8 * c + 7]);
            if (c == 0) {
                r2[0] = __fmul_rn(d0, d0); r2[1] = __fmul_rn(d1, d1);
                r2[2] = __fmul_rn(d2, d2); r2[3] = __fmul_rn(d3, d3);
                r2[4] = __fmul_rn(d4, d4); r2[5] = __fmul_rn(d5, d5);
                r2[6] = __fmul_rn(d6, d6); r2[7] = __fmul_rn(d7, d7);
            } else {
                r2[0] = __fadd_rn(r2[0], __fmul_rn(d0, d0));
                r2[1] = __fadd_rn(r2[1], __fmul_rn(d1, d1));
                r2[2] = __fadd_rn(r2[2], __fmul_rn(d2, d2));
                r2[3] = __fadd_rn(r2[3], __fmul_rn(d3, d3));
                r2[4] = __fadd_rn(r2[4], __fmul_rn(d4, d4));
                r2[5] = __fadd_rn(r2[5], __fmul_rn(d5, d5));
                r2[6] = __fadd_rn(r2[6], __fmul_rn(d6, d6));
                r2[7] = __fadd_rn(r2[7], __fmul_rn(d7, d7));
            }
        }
        float S = __fadd_rn(__fadd_rn(__fadd_rn(r2[0], r2[1]), __fadd_rn(r2[2], r2[3])),
                            __fadd_rn(__fadd_rn(r2[4], r2[5]), __fadd_rn(r2[6], r2[7])));
        float m = __fmul_rn(S, 0.015625f);
        out[NQ + NROWS + ng] = __fadd_rn(__fmul_rn(m, 0.1f), __fmul_rn(m, 0.2f));
    }
}

extern "C" void kernel_launch(void* const* d_in, const int* in_sizes, int n_in,
                              void* d_out, int out_size, void* d_ws, size_t ws_size,
                              hipStream_t stream) {
    (void)in_sizes; (void)n_in; (void)out_size; (void)ws_size;
    const float* h = (const float*)d_in[0];
    const float* w = (const float*)d_in[1];
    float* out = (float*)d_out;

    char* ws = (char*)d_ws;
    float* bsq = (float*)ws;                               // 4 KB
    float* wmaxp = (float*)(ws + 4096);                    // 16 B
    unsigned short* wbf = (unsigned short*)(ws + 8192);    // 128 KB

    prep_w<<<1, 1024, 0, stream>>>(w, bsq, wbf, wmaxp);
    vq_scan<<<NROWS / (WAVES * RPW), BLKT, 0, stream>>>(h, w, wbf, bsq, wmaxp, out);
}

// Round 18
// 319.939 us; speedup vs baseline: 1.0606x; 1.0413x over previous
//
#include <hip/hip_runtime.h>
#include <math.h>

#define NROWS (512 * 512)
#define KCB   1024
#define DDIM  64
#define NQ    ((size_t)NROWS * DDIM)
#define RPW   64            // rows per wave (4 mt tiles)
#define CMAX  8             // candidate cap per row
#define WAVES 4
#define BLKT  256
#define KPH   256           // codes per LDS phase (32 KB tile)
#define NTPH  (KPH / 16)    // 16 k-tiles per phase

typedef __attribute__((ext_vector_type(8))) short bf16x8;
typedef __attribute__((ext_vector_type(4))) float f32x4;

__device__ __forceinline__ unsigned short f2bf(float x) {
    unsigned u = __float_as_uint(x);
    u = u + 0x7FFFu + ((u >> 16) & 1u);
    return (unsigned short)(u >> 16);
}
__device__ __forceinline__ unsigned fsort(float d) {   // monotonic f32 -> u32
    unsigned u = __float_as_uint(d);
    return (u & 0x80000000u) ? ~u : (u | 0x80000000u);
}

// ---------- K1: frozen wsq + w->bf16 + wmax ----------
__global__ __launch_bounds__(1024)
void prep_w(const float* __restrict__ w, float* __restrict__ bsq,
            unsigned short* __restrict__ wbf, float* __restrict__ wmaxp) {
    __shared__ float red[16];
    const int k = threadIdx.x;
    const float* row = w + (size_t)k * DDIM;
    float r[8];
#pragma unroll
    for (int j = 0; j < 8; ++j) r[j] = __fmul_rn(row[j], row[j]);
#pragma unroll
    for (int i = 8; i < DDIM; i += 8)
#pragma unroll
        for (int j = 0; j < 8; ++j)
            r[j] = __fadd_rn(r[j], __fmul_rn(row[i + j], row[i + j]));
    float b = __fadd_rn(__fadd_rn(__fadd_rn(r[0], r[1]), __fadd_rn(r[2], r[3])),
                        __fadd_rn(__fadd_rn(r[4], r[5]), __fadd_rn(r[6], r[7])));
    bsq[k] = b;
    unsigned* dst = (unsigned*)(wbf + (size_t)k * DDIM);
#pragma unroll
    for (int j = 0; j < 32; ++j)
        dst[j] = (unsigned)f2bf(row[2 * j]) | ((unsigned)f2bf(row[2 * j + 1]) << 16);
    float v = sqrtf(b) * 1.02f;
#pragma unroll
    for (int off = 1; off < 64; off <<= 1) v = fmaxf(v, __shfl_xor(v, off));
    if ((threadIdx.x & 63) == 0) red[threadIdx.x >> 6] = v;
    __syncthreads();
    if (threadIdx.x == 0) {
        float m = red[0];
#pragma unroll
        for (int j = 1; j < 16; ++j) m = fmaxf(m, red[j]);
        *wmaxp = m;
    }
}

// ---------- K3: two-pass scan (R15 math), 4-wave blocks, RPW=64, 40KB LDS ----------
__global__ __launch_bounds__(BLKT, 4)
void vq_scan(const float* __restrict__ h, const float* __restrict__ w,
             const unsigned short* __restrict__ wbf, const float* __restrict__ bsq,
             const float* __restrict__ wmaxp, float* __restrict__ out) {
    // 32 KB swizzled codebook tile: row lr (0..255) x 8 float4 chunks;
    // chunk c stored at s4[lr*8 + (c ^ (lr&7))]  (XOR involution, 16B granularity)
    __shared__ float4 s4[KPH * 8];                       // 32768 B
    __shared__ float sbsq[KPH];                          //  1024 B
    __shared__ int scnt[WAVES][RPW];                     //  1024 B
    __shared__ unsigned short sclist[WAVES][RPW][CMAX];  //  4096 B
    __shared__ unsigned long long sbkey[WAVES][RPW];     //  2048 B   => 40960 total

    const int tid = threadIdx.x;
    const int wv = tid >> 6, lane = tid & 63;
    const int l16 = lane & 15, lh = lane >> 4;
    const int rowbase = blockIdx.x * (WAVES * RPW) + wv * RPW;   // wave's 64 rows

    scnt[wv][lane] = 0;
    sbkey[wv][lane] = 0xFFFFFFFFFFFFFFFFULL;

    // Af: frozen pairwise-8 — lane r computes row r (all 64 lanes active)
    float af;
    {
        const float* row = h + (size_t)(rowbase + lane) * DDIM;
        float hr[DDIM];
#pragma unroll
        for (int i = 0; i < DDIM; i += 4) {
            float4 v = *reinterpret_cast<const float4*>(row + i);
            hr[i] = v.x; hr[i + 1] = v.y; hr[i + 2] = v.z; hr[i + 3] = v.w;
        }
        float s[8];
#pragma unroll
        for (int j = 0; j < 8; ++j) s[j] = __fmul_rn(hr[j], hr[j]);
#pragma unroll
        for (int i = 8; i < DDIM; i += 8)
#pragma unroll
            for (int j = 0; j < 8; ++j)
                s[j] = __fadd_rn(s[j], __fmul_rn(hr[i + j], hr[i + j]));
        af = __fadd_rn(__fadd_rn(__fadd_rn(s[0], s[1]), __fadd_rn(s[2], s[3])),
                       __fadd_rn(__fadd_rn(s[4], s[5]), __fadd_rn(s[6], s[7])));
    }

    // A-frags (h rows, bf16) — 4 mt tiles, layout validated R10-R17
    bf16x8 afr[4][2];
#pragma unroll
    for (int mt = 0; mt < 4; ++mt) {
        const float* hrow = h + ((size_t)(rowbase + mt * 16 + l16)) * DDIM;
#pragma unroll
        for (int dh = 0; dh < 2; ++dh) {
            float4 a = *reinterpret_cast<const float4*>(hrow + dh * 32 + lh * 8);
            float4 bq = *reinterpret_cast<const float4*>(hrow + dh * 32 + lh * 8 + 4);
            union { bf16x8 v; unsigned short u[8]; } pk;
            pk.u[0] = f2bf(a.x); pk.u[1] = f2bf(a.y); pk.u[2] = f2bf(a.z); pk.u[3] = f2bf(a.w);
            pk.u[4] = f2bf(bq.x); pk.u[5] = f2bf(bq.y); pk.u[6] = f2bf(bq.z); pk.u[7] = f2bf(bq.w);
            afr[mt][dh] = pk.v;
        }
    }

    // per-lane constant swizzled chunk indices (lr&7 == l16&7 since nt*16 ≡ 0 mod 8)
    const int sw = l16 & 7;
    const int C0 = lh ^ sw;         // chunk for d0..31
    const int C1 = (4 + lh) ^ sw;   // chunk for d32..63

    float pmin[16];
#pragma unroll
    for (int j = 0; j < 16; ++j) pmin[j] = INFINITY;

    const float4* g4all = reinterpret_cast<const float4*>(wbf);

    // ================== PASS A: mins (4 staged phases of KPH=256) ==================
#pragma unroll 1
    for (int ph = 0; ph < 4; ++ph) {
        const int k0 = ph * KPH;
        __syncthreads();   // protect previous phase readers before overwrite
        const float4* g4 = g4all + (size_t)k0 * 8;
#pragma unroll
        for (int j = 0; j < 8; ++j) {
            int F = j * BLKT + tid;          // 0..2047 LDS float4 index
            int r = F >> 3, c = F & 7;
            s4[F] = g4[r * 8 + (c ^ (r & 7))];
        }
        sbsq[tid] = bsq[k0 + tid];
        __syncthreads();

        float4 pb0[2], pb1[2];
        float pbq[2];
#pragma unroll
        for (int q = 0; q < 2; ++q) {
            const int lr = q * 16 + l16;
            pb0[q] = s4[lr * 8 + C0];
            pb1[q] = s4[lr * 8 + C1];
            pbq[q] = sbsq[lr];
        }
#pragma unroll 4
        for (int nt = 0; nt < NTPH; ++nt) {
            const int s = nt & 1;
            float4 b0 = pb0[s], b1 = pb1[s];
            float bq = pbq[s];
            {
                const int ntn = (nt + 2 < NTPH) ? (nt + 2) : (NTPH - 1);
                const int lr = ntn * 16 + l16;
                pb0[s] = s4[lr * 8 + C0];
                pb1[s] = s4[lr * 8 + C1];
                pbq[s] = sbsq[lr];
            }
            bf16x8 bfr0 = *reinterpret_cast<const bf16x8*>(&b0);
            bf16x8 bfr1 = *reinterpret_cast<const bf16x8*>(&b1);
#pragma unroll
            for (int mt = 0; mt < 4; ++mt) {
                f32x4 acc = {0.f, 0.f, 0.f, 0.f};
                acc = __builtin_amdgcn_mfma_f32_16x16x32_bf16(afr[mt][0], bfr0, acc, 0, 0, 0);
                acc = __builtin_amdgcn_mfma_f32_16x16x32_bf16(afr[mt][1], bfr1, acc, 0, 0, 0);
#pragma unroll
                for (int i = 0; i < 4; ++i)
                    pmin[mt * 4 + i] = fminf(pmin[mt * 4 + i], bq - (acc[i] + acc[i]));
            }
        }
    }

    // butterfly min over the 16 l16-lanes; thresholds (validated margin formula)
#pragma unroll
    for (int off = 1; off < 16; off <<= 1)
#pragma unroll
        for (int j = 0; j < 16; ++j) pmin[j] = fminf(pmin[j], __shfl_xor(pmin[j], off));
    const float wmaxv = *wmaxp;
    float tr[16];
#pragma unroll
    for (int mt = 0; mt < 4; ++mt)
#pragma unroll
        for (int i = 0; i < 4; ++i) {
            float Afr = __shfl(af, mt * 16 + lh * 4 + i);
            tr[mt * 4 + i] = pmin[mt * 4 + i] + sqrtf(Afr) * 1.001f * wmaxv * 0.03125f + 1e-3f;
        }

    // ================== PASS B: candidates (re-staged phases) ==================
#pragma unroll 1
    for (int ph = 0; ph < 4; ++ph) {
        const int k0 = ph * KPH;
        __syncthreads();
        const float4* g4 = g4all + (size_t)k0 * 8;
#pragma unroll
        for (int j = 0; j < 8; ++j) {
            int F = j * BLKT + tid;
            int r = F >> 3, c = F & 7;
            s4[F] = g4[r * 8 + (c ^ (r & 7))];
        }
        sbsq[tid] = bsq[k0 + tid];
        __syncthreads();

        float4 pb0[2], pb1[2];
        float pbq[2];
#pragma unroll
        for (int q = 0; q < 2; ++q) {
            const int lr = q * 16 + l16;
            pb0[q] = s4[lr * 8 + C0];
            pb1[q] = s4[lr * 8 + C1];
            pbq[q] = sbsq[lr];
        }
#pragma unroll 4
        for (int nt = 0; nt < NTPH; ++nt) {
            const int s = nt & 1;
            float4 b0 = pb0[s], b1 = pb1[s];
            float bq = pbq[s];
            {
                const int ntn = (nt + 2 < NTPH) ? (nt + 2) : (NTPH - 1);
                const int lr = ntn * 16 + l16;
                pb0[s] = s4[lr * 8 + C0];
                pb1[s] = s4[lr * 8 + C1];
                pbq[s] = sbsq[lr];
            }
            bf16x8 bfr0 = *reinterpret_cast<const bf16x8*>(&b0);
            bf16x8 bfr1 = *reinterpret_cast<const bf16x8*>(&b1);
            const int kk = k0 + nt * 16 + l16;
#pragma unroll
            for (int mt = 0; mt < 4; ++mt) {
                f32x4 acc = {0.f, 0.f, 0.f, 0.f};
                acc = __builtin_amdgcn_mfma_f32_16x16x32_bf16(afr[mt][0], bfr0, acc, 0, 0, 0);
                acc = __builtin_amdgcn_mfma_f32_16x16x32_bf16(afr[mt][1], bfr1, acc, 0, 0, 0);
#pragma unroll
                for (int i = 0; i < 4; ++i) {
                    float val = bq - (acc[i] + acc[i]);
                    if (val <= tr[mt * 4 + i]) {
                        int row = mt * 16 + lh * 4 + i;
                        int slot = atomicAdd(&scnt[wv][row], 1);
                        if (slot < CMAX) sclist[wv][row][slot] = (unsigned short)kk;
                    }
                }
            }
        }
    }
    __builtin_amdgcn_wave_barrier();

    // ---- rescore: 1 lane per row (lane-local af), exact frozen chain ----
    {
        const int cnt = scnt[wv][lane];
        if (cnt <= CMAX) {
            const size_t ng = (size_t)rowbase + lane;
            const float* hrow = h + ng * DDIM;
            float hreg[DDIM];
#pragma unroll
            for (int i = 0; i < DDIM; i += 4) {
                float4 v = *reinterpret_cast<const float4*>(hrow + i);
                hreg[i] = v.x; hreg[i + 1] = v.y; hreg[i + 2] = v.z; hreg[i + 3] = v.w;
            }
            for (int slot = 0; slot < cnt; ++slot) {
                int k = sclist[wv][lane][slot];
                const float* wr = w + (size_t)k * DDIM;
                float acc = 0.f;
#pragma unroll
                for (int i = 0; i < DDIM; i += 4) {
                    float4 x = *reinterpret_cast<const float4*>(wr + i);
                    acc = fmaf(hreg[i + 0], x.x, acc);
                    acc = fmaf(hreg[i + 1], x.y, acc);
                    acc = fmaf(hreg[i + 2], x.z, acc);
                    acc = fmaf(hreg[i + 3], x.w, acc);
                }
                float d = __fsub_rn(__fadd_rn(af, bsq[k]), __fadd_rn(acc, acc));
                unsigned long long key = ((unsigned long long)fsort(d) << 32) | (unsigned)k;
                atomicMin(&sbkey[wv][lane], key);
            }
        }
    }
    // overflow fallback (exact full scan, wave-wide; rare)
#pragma unroll 1
    for (int r = 0; r < RPW; ++r) {
        if (scnt[wv][r] > CMAX) {
            const float Afr = __shfl(af, r);
            const size_t ng = (size_t)rowbase + r;
            const float* hrow = h + ng * DDIM;
            float hreg[DDIM];
#pragma unroll
            for (int i = 0; i < DDIM; i += 4) {
                float4 v = *reinterpret_cast<const float4*>(hrow + i);
                hreg[i] = v.x; hreg[i + 1] = v.y; hreg[i + 2] = v.z; hreg[i + 3] = v.w;
            }
            for (int k = lane; k < KCB; k += 64) {
                const float* wr = w + (size_t)k * DDIM;
                float acc = 0.f;
#pragma unroll
                for (int i = 0; i < DDIM; i += 4) {
                    float4 x = *reinterpret_cast<const float4*>(wr + i);
                    acc = fmaf(hreg[i + 0], x.x, acc);
                    acc = fmaf(hreg[i + 1], x.y, acc);
                    acc = fmaf(hreg[i + 2], x.z, acc);
                    acc = fmaf(hreg[i + 3], x.w, acc);
                }
                float d = __fsub_rn(__fadd_rn(Afr, bsq[k]), __fadd_rn(acc, acc));
                unsigned long long key = ((unsigned long long)fsort(d) << 32) | (unsigned)k;
                atomicMin(&sbkey[wv][r], key);
            }
        }
    }
    __builtin_amdgcn_wave_barrier();

    // ---- fused outputs (per wave) — frozen R13-R17 ----
    out[NQ + rowbase + lane] = (float)(unsigned)(sbkey[wv][lane] & 0xFFFFFFFFu);

    // qst: 64 rows x 16 float4 = 16 per lane; ops identical to validated K4
#pragma unroll
    for (int q = 0; q < 16; ++q) {
        const int idx = q * 64 + lane;          // 0..1023
        const int row = idx >> 4, c4 = idx & 15;
        const int bk = (int)(unsigned)(sbkey[wv][row] & 0xFFFFFFFFu);
        const size_t ng = (size_t)rowbase + row;
        float4 hq = *reinterpret_cast<const float4*>(h + ng * DDIM + 4 * c4);
        float4 wq = *reinterpret_cast<const float4*>(w + (size_t)bk * DDIM + 4 * c4);
        float4 o;
        o.x = __fadd_rn(hq.x, __fsub_rn(wq.x, hq.x));
        o.y = __fadd_rn(hq.y, __fsub_rn(wq.y, hq.y));
        o.z = __fadd_rn(hq.z, __fsub_rn(wq.z, hq.z));
        o.w = __fadd_rn(hq.w, __fsub_rn(wq.w, hq.w));
        *reinterpret_cast<float4*>(out + ng * DDIM + 4 * c4) = o;
    }

    // loss: all 64 lanes, one row each — verbatim frozen recipe (validated R2)
    {
        const int bk = (int)(unsigned)(sbkey[wv][lane] & 0xFFFFFFFFu);
        const size_t ng = (size_t)rowbase + lane;
        const float* hrow = h + ng * DDIM;
        const float* qrow = w + (size_t)bk * DDIM;
        float hr[DDIM];
#pragma unroll
        for (int i = 0; i < DDIM; i += 4) {
            float4 v = *reinterpret_cast<const float4*>(hrow + i);
            hr[i] = v.x; hr[i + 1] = v.y; hr[i + 2] = v.z; hr[i + 3] = v.w;
        }
        float r2[8];
#pragma unroll
        for (int c = 0; c < 8; ++c) {
            float4 qa = *reinterpret_cast<const float4*>(qrow + 8 * c);
            float4 qb = *reinterpret_cast<const float4*>(qrow + 8 * c + 4);
            float d0 = __fsub_rn(qa.x, hr[8 * c + 0]);
            float d1 = __fsub_rn(qa.y, hr[8 * c + 1]);
            float d2 = __fsub_rn(qa.z, hr[8 * c + 2]);
            float d3 = __fsub_rn(qa.w, hr[8 * c + 3]);
            float d4 = __fsub_rn(qb.x, hr[8 * c + 4]);
            float d5 = __fsub_rn(qb.y, hr[8 * c + 5]);
            float d6 = __fsub_rn(qb.z, hr[8 * c + 6]);
            float d7 = __fsub_rn(qb.w, hr[8 * c + 7]);
            if (c == 0) {
                r2[0] = __fmul_rn(d0, d0); r2[1] = __fmul_rn(d1, d1);
                r2[2] = __fmul_rn(d2, d2); r2[3] = __fmul_rn(d3, d3);
                r2[4] = __fmul_rn(d4, d4); r2[5] = __fmul_rn(d5, d5);
                r2[6] = __fmul_rn(d6, d6); r2[7] = __fmul_rn(d7, d7);
            } else {
                r2[0] = __fadd_rn(r2[0], __fmul_rn(d0, d0));
                r2[1] = __fadd_rn(r2[1], __fmul_rn(d1, d1));
                r2[2] = __fadd_rn(r2[2], __fmul_rn(d2, d2));
                r2[3] = __fadd_rn(r2[3], __fmul_rn(d3, d3));
                r2[4] = __fadd_rn(r2[4], __fmul_rn(d4, d4));
                r2[5] = __fadd_rn(r2[5], __fmul_rn(d5, d5));
                r2[6] = __fadd_rn(r2[6], __fmul_rn(d6, d6));
                r2[7] = __fadd_rn(r2[7], __fmul_rn(d7, d7));
            }
        }
        float S = __fadd_rn(__fadd_rn(__fadd_rn(r2[0], r2[1]), __fadd_rn(r2[2], r2[3])),
                            __fadd_rn(__fadd_rn(r2[4], r2[5]), __fadd_rn(r2[6], r2[7])));
        float m = __fmul_rn(S, 0.015625f);
        out[NQ + NROWS + ng] = __fadd_rn(__fmul_rn(m, 0.1f), __fmul_rn(m, 0.2f));
    }
}

extern "C" void kernel_launch(void* const* d_in, const int* in_sizes, int n_in,
                              void* d_out, int out_size, void* d_ws, size_t ws_size,
                              hipStream_t stream) {
    (void)in_sizes; (void)n_in; (void)out_size; (void)ws_size;
    const float* h = (const float*)d_in[0];
    const float* w = (const float*)d_in[1];
    float* out = (float*)d_out;

    char* ws = (char*)d_ws;
    float* bsq = (float*)ws;                               // 4 KB
    float* wmaxp = (float*)(ws + 4096);                    // 16 B
    unsigned short* wbf = (unsigned short*)(ws + 8192);    // 128 KB

    prep_w<<<1, 1024, 0, stream>>>(w, bsq, wbf, wmaxp);
    vq_scan<<<NROWS / (WAVES * RPW), BLKT, 0, stream>>>(h, w, wbf, bsq, wmaxp, out);
}

// Round 19
// 284.806 us; speedup vs baseline: 1.1914x; 1.1234x over previous
//
#include <hip/hip_runtime.h>
#include <math.h>

#define NROWS (512 * 512)
#define KCB   1024
#define DDIM  64
#define NQ    ((size_t)NROWS * DDIM)
#define RPW   32            // rows per group per wave
#define CMAX  8             // candidate cap per row
#define WAVES 8
#define BLKT  512
#define NBLK  256           // 1 block per CU, persistent
#define ITERS 4             // row-groups per wave: 256*8*4*32 = 262144

typedef __attribute__((ext_vector_type(8))) short bf16x8;
typedef __attribute__((ext_vector_type(4))) float f32x4;

__device__ __forceinline__ unsigned short f2bf(float x) {
    unsigned u = __float_as_uint(x);
    u = u + 0x7FFFu + ((u >> 16) & 1u);
    return (unsigned short)(u >> 16);
}
__device__ __forceinline__ unsigned fsort(float d) {   // monotonic f32 -> u32
    unsigned u = __float_as_uint(d);
    return (u & 0x80000000u) ? ~u : (u | 0x80000000u);
}

// ---------- K1: frozen wsq + w->bf16 + wmax ----------
__global__ __launch_bounds__(1024)
void prep_w(const float* __restrict__ w, float* __restrict__ bsq,
            unsigned short* __restrict__ wbf, float* __restrict__ wmaxp) {
    __shared__ float red[16];
    const int k = threadIdx.x;
    const float* row = w + (size_t)k * DDIM;
    float r[8];
#pragma unroll
    for (int j = 0; j < 8; ++j) r[j] = __fmul_rn(row[j], row[j]);
#pragma unroll
    for (int i = 8; i < DDIM; i += 8)
#pragma unroll
        for (int j = 0; j < 8; ++j)
            r[j] = __fadd_rn(r[j], __fmul_rn(row[i + j], row[i + j]));
    float b = __fadd_rn(__fadd_rn(__fadd_rn(r[0], r[1]), __fadd_rn(r[2], r[3])),
                        __fadd_rn(__fadd_rn(r[4], r[5]), __fadd_rn(r[6], r[7])));
    bsq[k] = b;
    unsigned* dst = (unsigned*)(wbf + (size_t)k * DDIM);
#pragma unroll
    for (int j = 0; j < 32; ++j)
        dst[j] = (unsigned)f2bf(row[2 * j]) | ((unsigned)f2bf(row[2 * j + 1]) << 16);
    float v = sqrtf(b) * 1.02f;
#pragma unroll
    for (int off = 1; off < 64; off <<= 1) v = fmaxf(v, __shfl_xor(v, off));
    if ((threadIdx.x & 63) == 0) red[threadIdx.x >> 6] = v;
    __syncthreads();
    if (threadIdx.x == 0) {
        float m = red[0];
#pragma unroll
        for (int j = 1; j < 16; ++j) m = fmaxf(m, red[j]);
        *wmaxp = m;
    }
}

// ---------- K3: persistent blocks, full 128KB codebook in LDS, no loop barriers ----------
__global__ __launch_bounds__(BLKT, 1)
void vq_scan(const float* __restrict__ h, const float* __restrict__ w,
             const unsigned short* __restrict__ wbf, const float* __restrict__ bsq,
             const float* __restrict__ wmaxp, float* __restrict__ out) {
    // full codebook, swizzled: row lr (0..1023) x 8 float4 chunks;
    // chunk c stored at s4[lr*8 + (c ^ (lr&7))]  (XOR involution, 16B granularity)
    __shared__ float4 s4[KCB * 8];                       // 131072 B
    __shared__ float sbsq[KCB];                          //   4096 B
    __shared__ int scnt[WAVES][RPW];                     //   1024 B
    __shared__ unsigned short sclist[WAVES][RPW][CMAX];  //   4096 B
    __shared__ unsigned long long sbkey[WAVES][RPW];     //   2048 B  => 142336 total

    const int tid = threadIdx.x;
    const int wv = tid >> 6, lane = tid & 63;
    const int l16 = lane & 15, lh = lane >> 4;

    // ---- one-time stage: whole codebook, linear LDS write + inverse-permuted read ----
    {
        const float4* g4 = reinterpret_cast<const float4*>(wbf);
#pragma unroll
        for (int j = 0; j < 16; ++j) {
            int F = j * BLKT + tid;          // 0..8191
            int r = F >> 3, c = F & 7;
            s4[F] = g4[r * 8 + (c ^ (r & 7))];
        }
        sbsq[tid] = bsq[tid];
        sbsq[tid + 512] = bsq[tid + 512];
    }
    __syncthreads();   // the only block barrier

    // per-lane constant swizzled chunk indices (lr ≡ l16 mod 8)
    const int sw = l16 & 7;
    const int C0 = lh ^ sw;         // chunk for d0..31
    const int C1 = (4 + lh) ^ sw;   // chunk for d32..63
    const float wmaxv = *wmaxp;

#pragma unroll 1
    for (int it = 0; it < ITERS; ++it) {
        const size_t rowbase = ((size_t)blockIdx.x * WAVES + wv) * (RPW * ITERS) + (size_t)it * RPW;

        if (lane < RPW) { scnt[wv][lane] = 0; sbkey[wv][lane] = 0xFFFFFFFFFFFFFFFFULL; }

        // Af: frozen pairwise-8 (lane r computes row r)
        float af = 0.f;
        if (lane < RPW) {
            const float* row = h + (size_t)(rowbase + lane) * DDIM;
            float hr[DDIM];
#pragma unroll
            for (int i = 0; i < DDIM; i += 4) {
                float4 v = *reinterpret_cast<const float4*>(row + i);
                hr[i] = v.x; hr[i + 1] = v.y; hr[i + 2] = v.z; hr[i + 3] = v.w;
            }
            float s[8];
#pragma unroll
            for (int j = 0; j < 8; ++j) s[j] = __fmul_rn(hr[j], hr[j]);
#pragma unroll
            for (int i = 8; i < DDIM; i += 8)
#pragma unroll
                for (int j = 0; j < 8; ++j)
                    s[j] = __fadd_rn(s[j], __fmul_rn(hr[i + j], hr[i + j]));
            af = __fadd_rn(__fadd_rn(__fadd_rn(s[0], s[1]), __fadd_rn(s[2], s[3])),
                           __fadd_rn(__fadd_rn(s[4], s[5]), __fadd_rn(s[6], s[7])));
        }

        // A-frags (h rows, bf16) — layout validated R10-R18
        bf16x8 afr[2][2];
#pragma unroll
        for (int mt = 0; mt < 2; ++mt) {
            const float* hrow = h + ((size_t)(rowbase + mt * 16 + l16)) * DDIM;
#pragma unroll
            for (int dh = 0; dh < 2; ++dh) {
                float4 a = *reinterpret_cast<const float4*>(hrow + dh * 32 + lh * 8);
                float4 bq = *reinterpret_cast<const float4*>(hrow + dh * 32 + lh * 8 + 4);
                union { bf16x8 v; unsigned short u[8]; } pk;
                pk.u[0] = f2bf(a.x); pk.u[1] = f2bf(a.y); pk.u[2] = f2bf(a.z); pk.u[3] = f2bf(a.w);
                pk.u[4] = f2bf(bq.x); pk.u[5] = f2bf(bq.y); pk.u[6] = f2bf(bq.z); pk.u[7] = f2bf(bq.w);
                afr[mt][dh] = pk.v;
            }
        }

        // ---- PASS A: mins; 8 chunks x (16 ds_read_b128 issued wide, then 16 MFMA) ----
        float pmin[8];
#pragma unroll
        for (int j = 0; j < 8; ++j) pmin[j] = INFINITY;

#pragma unroll 1
        for (int ch = 0; ch < 8; ++ch) {
            float4 cb0[8], cb1[8];
            float cbq[8];
#pragma unroll
            for (int t = 0; t < 8; ++t) {
                const int lr = (ch * 8 + t) * 16 + l16;
                cb0[t] = s4[lr * 8 + C0];
                cb1[t] = s4[lr * 8 + C1];
                cbq[t] = sbsq[lr];
            }
#pragma unroll
            for (int t = 0; t < 8; ++t) {
                bf16x8 bfr0 = *reinterpret_cast<const bf16x8*>(&cb0[t]);
                bf16x8 bfr1 = *reinterpret_cast<const bf16x8*>(&cb1[t]);
#pragma unroll
                for (int mt = 0; mt < 2; ++mt) {
                    f32x4 acc = {0.f, 0.f, 0.f, 0.f};
                    acc = __builtin_amdgcn_mfma_f32_16x16x32_bf16(afr[mt][0], bfr0, acc, 0, 0, 0);
                    acc = __builtin_amdgcn_mfma_f32_16x16x32_bf16(afr[mt][1], bfr1, acc, 0, 0, 0);
#pragma unroll
                    for (int i = 0; i < 4; ++i)
                        pmin[mt * 4 + i] = fminf(pmin[mt * 4 + i], cbq[t] - (acc[i] + acc[i]));
                }
            }
        }

        // butterfly min over the 16 l16-lanes; thresholds (validated margin formula)
#pragma unroll
        for (int off = 1; off < 16; off <<= 1)
#pragma unroll
            for (int j = 0; j < 8; ++j) pmin[j] = fminf(pmin[j], __shfl_xor(pmin[j], off));
        float tr[8];
#pragma unroll
        for (int mt = 0; mt < 2; ++mt)
#pragma unroll
            for (int i = 0; i < 4; ++i) {
                float Afr = __shfl(af, mt * 16 + lh * 4 + i);
                tr[mt * 4 + i] = pmin[mt * 4 + i] + sqrtf(Afr) * 1.001f * wmaxv * 0.03125f + 1e-3f;
            }

        // ---- PASS B: candidates (recompute from resident LDS; bitwise == pass A) ----
#pragma unroll 1
        for (int ch = 0; ch < 8; ++ch) {
            float4 cb0[8], cb1[8];
            float cbq[8];
#pragma unroll
            for (int t = 0; t < 8; ++t) {
                const int lr = (ch * 8 + t) * 16 + l16;
                cb0[t] = s4[lr * 8 + C0];
                cb1[t] = s4[lr * 8 + C1];
                cbq[t] = sbsq[lr];
            }
#pragma unroll
            for (int t = 0; t < 8; ++t) {
                bf16x8 bfr0 = *reinterpret_cast<const bf16x8*>(&cb0[t]);
                bf16x8 bfr1 = *reinterpret_cast<const bf16x8*>(&cb1[t]);
                const int kk = (ch * 8 + t) * 16 + l16;
#pragma unroll
                for (int mt = 0; mt < 2; ++mt) {
                    f32x4 acc = {0.f, 0.f, 0.f, 0.f};
                    acc = __builtin_amdgcn_mfma_f32_16x16x32_bf16(afr[mt][0], bfr0, acc, 0, 0, 0);
                    acc = __builtin_amdgcn_mfma_f32_16x16x32_bf16(afr[mt][1], bfr1, acc, 0, 0, 0);
#pragma unroll
                    for (int i = 0; i < 4; ++i) {
                        float val = cbq[t] - (acc[i] + acc[i]);
                        if (val <= tr[mt * 4 + i]) {
                            int row = mt * 16 + lh * 4 + i;
                            int slot = atomicAdd(&scnt[wv][row], 1);
                            if (slot < CMAX) sclist[wv][row][slot] = (unsigned short)kk;
                        }
                    }
                }
            }
        }
        __builtin_amdgcn_wave_barrier();

        // ---- rescore: 2 lanes/row, exact frozen chain, (d,k) atomicMin key ----
        {
            const int row = lane >> 1;
            const int s0 = lane & 1;
            const float Afr = __shfl(af, row);
            const int cnt = scnt[wv][row];
            if (cnt <= CMAX && s0 < cnt) {
                const size_t ng = rowbase + row;
                const float* hrow = h + ng * DDIM;
                float hreg[DDIM];
#pragma unroll
                for (int i = 0; i < DDIM; i += 4) {
                    float4 v = *reinterpret_cast<const float4*>(hrow + i);
                    hreg[i] = v.x; hreg[i + 1] = v.y; hreg[i + 2] = v.z; hreg[i + 3] = v.w;
                }
                for (int slot = s0; slot < cnt; slot += 2) {
                    int k = sclist[wv][row][slot];
                    const float* wr = w + (size_t)k * DDIM;
                    float acc = 0.f;
#pragma unroll
                    for (int i = 0; i < DDIM; i += 4) {
                        float4 x = *reinterpret_cast<const float4*>(wr + i);
                        acc = fmaf(hreg[i + 0], x.x, acc);
                        acc = fmaf(hreg[i + 1], x.y, acc);
                        acc = fmaf(hreg[i + 2], x.z, acc);
                        acc = fmaf(hreg[i + 3], x.w, acc);
                    }
                    float d = __fsub_rn(__fadd_rn(Afr, bsq[k]), __fadd_rn(acc, acc));
                    unsigned long long key = ((unsigned long long)fsort(d) << 32) | (unsigned)k;
                    atomicMin(&sbkey[wv][row], key);
                }
            }
        }
        // overflow fallback (exact full scan, wave-wide; rare)
#pragma unroll 1
        for (int r = 0; r < RPW; ++r) {
            const float Afr = __shfl(af, r);
            if (scnt[wv][r] > CMAX) {
                const size_t ng = rowbase + r;
                const float* hrow = h + ng * DDIM;
                float hreg[DDIM];
#pragma unroll
                for (int i = 0; i < DDIM; i += 4) {
                    float4 v = *reinterpret_cast<const float4*>(hrow + i);
                    hreg[i] = v.x; hreg[i + 1] = v.y; hreg[i + 2] = v.z; hreg[i + 3] = v.w;
                }
                for (int k = lane; k < KCB; k += 64) {
                    const float* wr = w + (size_t)k * DDIM;
                    float acc = 0.f;
#pragma unroll
                    for (int i = 0; i < DDIM; i += 4) {
                        float4 x = *reinterpret_cast<const float4*>(wr + i);
                        acc = fmaf(hreg[i + 0], x.x, acc);
                        acc = fmaf(hreg[i + 1], x.y, acc);
                        acc = fmaf(hreg[i + 2], x.z, acc);
                        acc = fmaf(hreg[i + 3], x.w, acc);
                    }
                    float d = __fsub_rn(__fadd_rn(Afr, bsq[k]), __fadd_rn(acc, acc));
                    unsigned long long key = ((unsigned long long)fsort(d) << 32) | (unsigned)k;
                    atomicMin(&sbkey[wv][r], key);
                }
            }
        }
        __builtin_amdgcn_wave_barrier();

        // ---- fused outputs (per wave) — frozen R13-R18 ----
        if (lane < RPW)
            out[NQ + rowbase + lane] = (float)(unsigned)(sbkey[wv][lane] & 0xFFFFFFFFu);

#pragma unroll
        for (int q = 0; q < 8; ++q) {
            const int idx = q * 64 + lane;
            const int row = idx >> 4, c4 = idx & 15;
            const int bk = (int)(unsigned)(sbkey[wv][row] & 0xFFFFFFFFu);
            const size_t ng = rowbase + row;
            float4 hq = *reinterpret_cast<const float4*>(h + ng * DDIM + 4 * c4);
            float4 wq = *reinterpret_cast<const float4*>(w + (size_t)bk * DDIM + 4 * c4);
            float4 o;
            o.x = __fadd_rn(hq.x, __fsub_rn(wq.x, hq.x));
            o.y = __fadd_rn(hq.y, __fsub_rn(wq.y, hq.y));
            o.z = __fadd_rn(hq.z, __fsub_rn(wq.z, hq.z));
            o.w = __fadd_rn(hq.w, __fsub_rn(wq.w, hq.w));
            *reinterpret_cast<float4*>(out + ng * DDIM + 4 * c4) = o;
        }

        if (lane < RPW) {
            const int bk = (int)(unsigned)(sbkey[wv][lane] & 0xFFFFFFFFu);
            const size_t ng = rowbase + lane;
            const float* hrow = h + ng * DDIM;
            const float* qrow = w + (size_t)bk * DDIM;
            float hr[DDIM];
#pragma unroll
            for (int i = 0; i < DDIM; i += 4) {
                float4 v = *reinterpret_cast<const float4*>(hrow + i);
                hr[i] = v.x; hr[i + 1] = v.y; hr[i + 2] = v.z; hr[i + 3] = v.w;
            }
            float r2[8];
#pragma unroll
            for (int c = 0; c < 8; ++c) {
                float4 qa = *reinterpret_cast<const float4*>(qrow + 8 * c);
                float4 qb = *reinterpret_cast<const float4*>(qrow + 8 * c + 4);
                float d0 = __fsub_rn(qa.x, hr[8 * c + 0]);
                float d1 = __fsub_rn(qa.y, hr[8 * c + 1]);
                float d2 = __fsub_rn(qa.z, hr[8 * c + 2]);
                float d3 = __fsub_rn(qa.w, hr[8 * c + 3]);
                float d4 = __fsub_rn(qb.x, hr[8 * c + 4]);
                float d5 = __fsub_rn(qb.y, hr[8 * c + 5]);
                float d6 = __fsub_rn(qb.z, hr[8 * c + 6]);
                float d7 = __fsub_rn(qb.w, hr[8 * c + 7]);
                if (c == 0) {
                    r2[0] = __fmul_rn(d0, d0); r2[1] = __fmul_rn(d1, d1);
                    r2[2] = __fmul_rn(d2, d2); r2[3] = __fmul_rn(d3, d3);
                    r2[4] = __fmul_rn(d4, d4); r2[5] = __fmul_rn(d5, d5);
                    r2[6] = __fmul_rn(d6, d6); r2[7] = __fmul_rn(d7, d7);
                } else {
                    r2[0] = __fadd_rn(r2[0], __fmul_rn(d0, d0));
                    r2[1] = __fadd_rn(r2[1], __fmul_rn(d1, d1));
                    r2[2] = __fadd_rn(r2[2], __fmul_rn(d2, d2));
                    r2[3] = __fadd_rn(r2[3], __fmul_rn(d3, d3));
                    r2[4] = __fadd_rn(r2[4], __fmul_rn(d4, d4));
                    r2[5] = __fadd_rn(r2[5], __fmul_rn(d5, d5));
                    r2[6] = __fadd_rn(r2[6], __fmul_rn(d6, d6));
                    r2[7] = __fadd_rn(r2[7], __fmul_rn(d7, d7));
                }
            }
            float S = __fadd_rn(__fadd_rn(__fadd_rn(r2[0], r2[1]), __fadd_rn(r2[2], r2[3])),
                                __fadd_rn(__fadd_rn(r2[4], r2[5]), __fadd_rn(r2[6], r2[7])));
            float m = __fmul_rn(S, 0.015625f);
            out[NQ + NROWS + ng] = __fadd_rn(__fmul_rn(m, 0.1f), __fmul_rn(m, 0.2f));
        }
    }
}

extern "C" void kernel_launch(void* const* d_in, const int* in_sizes, int n_in,
                              void* d_out, int out_size, void* d_ws, size_t ws_size,
                              hipStream_t stream) {
    (void)in_sizes; (void)n_in; (void)out_size; (void)ws_size;
    const float* h = (const float*)d_in[0];
    const float* w = (const float*)d_in[1];
    float* out = (float*)d_out;

    char* ws = (char*)d_ws;
    float* bsq = (float*)ws;                               // 4 KB
    float* wmaxp = (float*)(ws + 4096);                    // 16 B
    unsigned short* wbf = (unsigned short*)(ws + 8192);    // 128 KB

    prep_w<<<1, 1024, 0, stream>>>(w, bsq, wbf, wmaxp);
    vq_scan<<<NBLK, BLKT, 0, stream>>>(h, w, wbf, bsq, wmaxp, out);
}

// Round 20
// 261.585 us; speedup vs baseline: 1.2971x; 1.0888x over previous
//
#include <hip/hip_runtime.h>
#include <math.h>

#define NROWS (512 * 512)
#define KCB   1024
#define DDIM  64
#define NQ    ((size_t)NROWS * DDIM)
#define RPW   32            // rows per group per wave
#define CMAX  8             // candidate cap per row
#define WAVES 16
#define BLKT  1024
#define NBLK  256           // 1 block per CU, persistent
#define ITERS 2             // row-groups per wave: 256*16*2*32 = 262144

typedef __attribute__((ext_vector_type(8))) short bf16x8;
typedef __attribute__((ext_vector_type(4))) float f32x4;

__device__ __forceinline__ unsigned short f2bf(float x) {
    unsigned u = __float_as_uint(x);
    u = u + 0x7FFFu + ((u >> 16) & 1u);
    return (unsigned short)(u >> 16);
}
__device__ __forceinline__ unsigned fsort(float d) {   // monotonic f32 -> u32
    unsigned u = __float_as_uint(d);
    return (u & 0x80000000u) ? ~u : (u | 0x80000000u);
}

// ---------- K1: frozen wsq + w->bf16 + wmax ----------
__global__ __launch_bounds__(1024)
void prep_w(const float* __restrict__ w, float* __restrict__ bsq,
            unsigned short* __restrict__ wbf, float* __restrict__ wmaxp) {
    __shared__ float red[16];
    const int k = threadIdx.x;
    const float* row = w + (size_t)k * DDIM;
    float r[8];
#pragma unroll
    for (int j = 0; j < 8; ++j) r[j] = __fmul_rn(row[j], row[j]);
#pragma unroll
    for (int i = 8; i < DDIM; i += 8)
#pragma unroll
        for (int j = 0; j < 8; ++j)
            r[j] = __fadd_rn(r[j], __fmul_rn(row[i + j], row[i + j]));
    float b = __fadd_rn(__fadd_rn(__fadd_rn(r[0], r[1]), __fadd_rn(r[2], r[3])),
                        __fadd_rn(__fadd_rn(r[4], r[5]), __fadd_rn(r[6], r[7])));
    bsq[k] = b;
    unsigned* dst = (unsigned*)(wbf + (size_t)k * DDIM);
#pragma unroll
    for (int j = 0; j < 32; ++j)
        dst[j] = (unsigned)f2bf(row[2 * j]) | ((unsigned)f2bf(row[2 * j + 1]) << 16);
    float v = sqrtf(b) * 1.02f;
#pragma unroll
    for (int off = 1; off < 64; off <<= 1) v = fmaxf(v, __shfl_xor(v, off));
    if ((threadIdx.x & 63) == 0) red[threadIdx.x >> 6] = v;
    __syncthreads();
    if (threadIdx.x == 0) {
        float m = red[0];
#pragma unroll
        for (int j = 1; j < 16; ++j) m = fmaxf(m, red[j]);
        *wmaxp = m;
    }
}

// ---------- K3: persistent 1024-thread blocks (4 waves/SIMD), codebook in LDS ----------
__global__ __launch_bounds__(BLKT, 1)
void vq_scan(const float* __restrict__ h, const float* __restrict__ w,
             const unsigned short* __restrict__ wbf, const float* __restrict__ bsq,
             const float* __restrict__ wmaxp, float* __restrict__ out) {
    // full codebook, swizzled: row lr (0..1023) x 8 float4 chunks;
    // chunk c stored at s4[lr*8 + (c ^ (lr&7))]  (XOR involution, 16B granularity)
    __shared__ float4 s4[KCB * 8];                       // 131072 B
    __shared__ float sbsq[KCB];                          //   4096 B
    __shared__ int scnt[WAVES][RPW];                     //   2048 B
    __shared__ unsigned short sclist[WAVES][RPW][CMAX];  //   8192 B
    __shared__ unsigned long long sbkey[WAVES][RPW];     //   4096 B  => 149504 total

    const int tid = threadIdx.x;
    const int wv = tid >> 6, lane = tid & 63;
    const int l16 = lane & 15, lh = lane >> 4;

    // ---- one-time stage: whole codebook, linear LDS write + inverse-permuted read ----
    {
        const float4* g4 = reinterpret_cast<const float4*>(wbf);
#pragma unroll
        for (int j = 0; j < 8; ++j) {
            int F = j * BLKT + tid;          // 0..8191
            int r = F >> 3, c = F & 7;
            s4[F] = g4[r * 8 + (c ^ (r & 7))];
        }
        sbsq[tid] = bsq[tid];
    }
    __syncthreads();   // the only block barrier

    // per-lane constant swizzled chunk indices (lr ≡ l16 mod 8)
    const int sw = l16 & 7;
    const int C0 = lh ^ sw;         // chunk for d0..31
    const int C1 = (4 + lh) ^ sw;   // chunk for d32..63
    const float wmaxv = *wmaxp;

#pragma unroll 1
    for (int it = 0; it < ITERS; ++it) {
        const size_t rowbase = ((size_t)blockIdx.x * WAVES + wv) * (RPW * ITERS) + (size_t)it * RPW;

        if (lane < RPW) { scnt[wv][lane] = 0; sbkey[wv][lane] = 0xFFFFFFFFFFFFFFFFULL; }

        // Af: frozen pairwise-8 (lane r computes row r)
        float af = 0.f;
        if (lane < RPW) {
            const float* row = h + (size_t)(rowbase + lane) * DDIM;
            float hr[DDIM];
#pragma unroll
            for (int i = 0; i < DDIM; i += 4) {
                float4 v = *reinterpret_cast<const float4*>(row + i);
                hr[i] = v.x; hr[i + 1] = v.y; hr[i + 2] = v.z; hr[i + 3] = v.w;
            }
            float s[8];
#pragma unroll
            for (int j = 0; j < 8; ++j) s[j] = __fmul_rn(hr[j], hr[j]);
#pragma unroll
            for (int i = 8; i < DDIM; i += 8)
#pragma unroll
                for (int j = 0; j < 8; ++j)
                    s[j] = __fadd_rn(s[j], __fmul_rn(hr[i + j], hr[i + j]));
            af = __fadd_rn(__fadd_rn(__fadd_rn(s[0], s[1]), __fadd_rn(s[2], s[3])),
                           __fadd_rn(__fadd_rn(s[4], s[5]), __fadd_rn(s[6], s[7])));
        }

        // A-frags (h rows, bf16) — layout validated R10-R19
        bf16x8 afr[2][2];
#pragma unroll
        for (int mt = 0; mt < 2; ++mt) {
            const float* hrow = h + ((size_t)(rowbase + mt * 16 + l16)) * DDIM;
#pragma unroll
            for (int dh = 0; dh < 2; ++dh) {
                float4 a = *reinterpret_cast<const float4*>(hrow + dh * 32 + lh * 8);
                float4 bq = *reinterpret_cast<const float4*>(hrow + dh * 32 + lh * 8 + 4);
                union { bf16x8 v; unsigned short u[8]; } pk;
                pk.u[0] = f2bf(a.x); pk.u[1] = f2bf(a.y); pk.u[2] = f2bf(a.z); pk.u[3] = f2bf(a.w);
                pk.u[4] = f2bf(bq.x); pk.u[5] = f2bf(bq.y); pk.u[6] = f2bf(bq.z); pk.u[7] = f2bf(bq.w);
                afr[mt][dh] = pk.v;
            }
        }

        // ---- PASS A: mins; 8 chunks x (16 ds_read_b128 issued wide, then 16 MFMA) ----
        float pmin[8];
#pragma unroll
        for (int j = 0; j < 8; ++j) pmin[j] = INFINITY;

#pragma unroll 1
        for (int ch = 0; ch < 8; ++ch) {
            float4 cb0[8], cb1[8];
            float cbq[8];
#pragma unroll
            for (int t = 0; t < 8; ++t) {
                const int lr = (ch * 8 + t) * 16 + l16;
                cb0[t] = s4[lr * 8 + C0];
                cb1[t] = s4[lr * 8 + C1];
                cbq[t] = sbsq[lr];
            }
#pragma unroll
            for (int t = 0; t < 8; ++t) {
                bf16x8 bfr0 = *reinterpret_cast<const bf16x8*>(&cb0[t]);
                bf16x8 bfr1 = *reinterpret_cast<const bf16x8*>(&cb1[t]);
#pragma unroll
                for (int mt = 0; mt < 2; ++mt) {
                    f32x4 acc = {0.f, 0.f, 0.f, 0.f};
                    acc = __builtin_amdgcn_mfma_f32_16x16x32_bf16(afr[mt][0], bfr0, acc, 0, 0, 0);
                    acc = __builtin_amdgcn_mfma_f32_16x16x32_bf16(afr[mt][1], bfr1, acc, 0, 0, 0);
#pragma unroll
                    for (int i = 0; i < 4; ++i)
                        pmin[mt * 4 + i] = fminf(pmin[mt * 4 + i], cbq[t] - (acc[i] + acc[i]));
                }
            }
        }

        // butterfly min over the 16 l16-lanes; thresholds (validated margin formula)
#pragma unroll
        for (int off = 1; off < 16; off <<= 1)
#pragma unroll
            for (int j = 0; j < 8; ++j) pmin[j] = fminf(pmin[j], __shfl_xor(pmin[j], off));
        float tr[8];
#pragma unroll
        for (int mt = 0; mt < 2; ++mt)
#pragma unroll
            for (int i = 0; i < 4; ++i) {
                float Afr = __shfl(af, mt * 16 + lh * 4 + i);
                tr[mt * 4 + i] = pmin[mt * 4 + i] + sqrtf(Afr) * 1.001f * wmaxv * 0.03125f + 1e-3f;
            }

        // ---- PASS B: candidates (recompute from resident LDS; bitwise == pass A) ----
#pragma unroll 1
        for (int ch = 0; ch < 8; ++ch) {
            float4 cb0[8], cb1[8];
            float cbq[8];
#pragma unroll
            for (int t = 0; t < 8; ++t) {
                const int lr = (ch * 8 + t) * 16 + l16;
                cb0[t] = s4[lr * 8 + C0];
                cb1[t] = s4[lr * 8 + C1];
                cbq[t] = sbsq[lr];
            }
#pragma unroll
            for (int t = 0; t < 8; ++t) {
                bf16x8 bfr0 = *reinterpret_cast<const bf16x8*>(&cb0[t]);
                bf16x8 bfr1 = *reinterpret_cast<const bf16x8*>(&cb1[t]);
                const int kk = (ch * 8 + t) * 16 + l16;
#pragma unroll
                for (int mt = 0; mt < 2; ++mt) {
                    f32x4 acc = {0.f, 0.f, 0.f, 0.f};
                    acc = __builtin_amdgcn_mfma_f32_16x16x32_bf16(afr[mt][0], bfr0, acc, 0, 0, 0);
                    acc = __builtin_amdgcn_mfma_f32_16x16x32_bf16(afr[mt][1], bfr1, acc, 0, 0, 0);
#pragma unroll
                    for (int i = 0; i < 4; ++i) {
                        float val = cbq[t] - (acc[i] + acc[i]);
                        if (val <= tr[mt * 4 + i]) {
                            int row = mt * 16 + lh * 4 + i;
                            int slot = atomicAdd(&scnt[wv][row], 1);
                            if (slot < CMAX) sclist[wv][row][slot] = (unsigned short)kk;
                        }
                    }
                }
            }
        }
        __builtin_amdgcn_wave_barrier();

        // ---- rescore: 2 lanes/row, exact frozen chain, (d,k) atomicMin key ----
        {
            const int row = lane >> 1;
            const int s0 = lane & 1;
            const float Afr = __shfl(af, row);
            const int cnt = scnt[wv][row];
            if (cnt <= CMAX && s0 < cnt) {
                const size_t ng = rowbase + row;
                const float* hrow = h + ng * DDIM;
                float hreg[DDIM];
#pragma unroll
                for (int i = 0; i < DDIM; i += 4) {
                    float4 v = *reinterpret_cast<const float4*>(hrow + i);
                    hreg[i] = v.x; hreg[i + 1] = v.y; hreg[i + 2] = v.z; hreg[i + 3] = v.w;
                }
                for (int slot = s0; slot < cnt; slot += 2) {
                    int k = sclist[wv][row][slot];
                    const float* wr = w + (size_t)k * DDIM;
                    float acc = 0.f;
#pragma unroll
                    for (int i = 0; i < DDIM; i += 4) {
                        float4 x = *reinterpret_cast<const float4*>(wr + i);
                        acc = fmaf(hreg[i + 0], x.x, acc);
                        acc = fmaf(hreg[i + 1], x.y, acc);
                        acc = fmaf(hreg[i + 2], x.z, acc);
                        acc = fmaf(hreg[i + 3], x.w, acc);
                    }
                    float d = __fsub_rn(__fadd_rn(Afr, bsq[k]), __fadd_rn(acc, acc));
                    unsigned long long key = ((unsigned long long)fsort(d) << 32) | (unsigned)k;
                    atomicMin(&sbkey[wv][row], key);
                }
            }
        }
        // overflow fallback (exact full scan, wave-wide; rare)
#pragma unroll 1
        for (int r = 0; r < RPW; ++r) {
            const float Afr = __shfl(af, r);
            if (scnt[wv][r] > CMAX) {
                const size_t ng = rowbase + r;
                const float* hrow = h + ng * DDIM;
                float hreg[DDIM];
#pragma unroll
                for (int i = 0; i < DDIM; i += 4) {
                    float4 v = *reinterpret_cast<const float4*>(hrow + i);
                    hreg[i] = v.x; hreg[i + 1] = v.y; hreg[i + 2] = v.z; hreg[i + 3] = v.w;
                }
                for (int k = lane; k < KCB; k += 64) {
                    const float* wr = w + (size_t)k * DDIM;
                    float acc = 0.f;
#pragma unroll
                    for (int i = 0; i < DDIM; i += 4) {
                        float4 x = *reinterpret_cast<const float4*>(wr + i);
                        acc = fmaf(hreg[i + 0], x.x, acc);
                        acc = fmaf(hreg[i + 1], x.y, acc);
                        acc = fmaf(hreg[i + 2], x.z, acc);
                        acc = fmaf(hreg[i + 3], x.w, acc);
                    }
                    float d = __fsub_rn(__fadd_rn(Afr, bsq[k]), __fadd_rn(acc, acc));
                    unsigned long long key = ((unsigned long long)fsort(d) << 32) | (unsigned)k;
                    atomicMin(&sbkey[wv][r], key);
                }
            }
        }
        __builtin_amdgcn_wave_barrier();

        // ---- fused outputs (per wave) — frozen R13-R19 ----
        if (lane < RPW)
            out[NQ + rowbase + lane] = (float)(unsigned)(sbkey[wv][lane] & 0xFFFFFFFFu);

#pragma unroll
        for (int q = 0; q < 8; ++q) {
            const int idx = q * 64 + lane;
            const int row = idx >> 4, c4 = idx & 15;
            const int bk = (int)(unsigned)(sbkey[wv][row] & 0xFFFFFFFFu);
            const size_t ng = rowbase + row;
            float4 hq = *reinterpret_cast<const float4*>(h + ng * DDIM + 4 * c4);
            float4 wq = *reinterpret_cast<const float4*>(w + (size_t)bk * DDIM + 4 * c4);
            float4 o;
            o.x = __fadd_rn(hq.x, __fsub_rn(wq.x, hq.x));
            o.y = __fadd_rn(hq.y, __fsub_rn(wq.y, hq.y));
            o.z = __fadd_rn(hq.z, __fsub_rn(wq.z, hq.z));
            o.w = __fadd_rn(hq.w, __fsub_rn(wq.w, hq.w));
            *reinterpret_cast<float4*>(out + ng * DDIM + 4 * c4) = o;
        }

        if (lane < RPW) {
            const int bk = (int)(unsigned)(sbkey[wv][lane] & 0xFFFFFFFFu);
            const size_t ng = rowbase + lane;
            const float* hrow = h + ng * DDIM;
            const float* qrow = w + (size_t)bk * DDIM;
            float hr[DDIM];
#pragma unroll
            for (int i = 0; i < DDIM; i += 4) {
                float4 v = *reinterpret_cast<const float4*>(hrow + i);
                hr[i] = v.x; hr[i + 1] = v.y; hr[i + 2] = v.z; hr[i + 3] = v.w;
            }
            float r2[8];
#pragma unroll
            for (int c = 0; c < 8; ++c) {
                float4 qa = *reinterpret_cast<const float4*>(qrow + 8 * c);
                float4 qb = *reinterpret_cast<const float4*>(qrow + 8 * c + 4);
                float d0 = __fsub_rn(qa.x, hr[8 * c + 0]);
                float d1 = __fsub_rn(qa.y, hr[8 * c + 1]);
                float d2 = __fsub_rn(qa.z, hr[8 * c + 2]);
                float d3 = __fsub_rn(qa.w, hr[8 * c + 3]);
                float d4 = __fsub_rn(qb.x, hr[8 * c + 4]);
                float d5 = __fsub_rn(qb.y, hr[8 * c + 5]);
                float d6 = __fsub_rn(qb.z, hr[8 * c + 6]);
                float d7 = __fsub_rn(qb.w, hr[8 * c + 7]);
                if (c == 0) {
                    r2[0] = __fmul_rn(d0, d0); r2[1] = __fmul_rn(d1, d1);
                    r2[2] = __fmul_rn(d2, d2); r2[3] = __fmul_rn(d3, d3);
                    r2[4] = __fmul_rn(d4, d4); r2[5] = __fmul_rn(d5, d5);
                    r2[6] = __fmul_rn(d6, d6); r2[7] = __fmul_rn(d7, d7);
                } else {
                    r2[0] = __fadd_rn(r2[0], __fmul_rn(d0, d0));
                    r2[1] = __fadd_rn(r2[1], __fmul_rn(d1, d1));
                    r2[2] = __fadd_rn(r2[2], __fmul_rn(d2, d2));
                    r2[3] = __fadd_rn(r2[3], __fmul_rn(d3, d3));
                    r2[4] = __fadd_rn(r2[4], __fmul_rn(d4, d4));
                    r2[5] = __fadd_rn(r2[5], __fmul_rn(d5, d5));
                    r2[6] = __fadd_rn(r2[6], __fmul_rn(d6, d6));
                    r2[7] = __fadd_rn(r2[7], __fmul_rn(d7, d7));
                }
            }
            float S = __fadd_rn(__fadd_rn(__fadd_rn(r2[0], r2[1]), __fadd_rn(r2[2], r2[3])),
                                __fadd_rn(__fadd_rn(r2[4], r2[5]), __fadd_rn(r2[6], r2[7])));
            float m = __fmul_rn(S, 0.015625f);
            out[NQ + NROWS + ng] = __fadd_rn(__fmul_rn(m, 0.1f), __fmul_rn(m, 0.2f));
        }
    }
}

extern "C" void kernel_launch(void* const* d_in, const int* in_sizes, int n_in,
                              void* d_out, int out_size, void* d_ws, size_t ws_size,
                              hipStream_t stream) {
    (void)in_sizes; (void)n_in; (void)out_size; (void)ws_size;
    const float* h = (const float*)d_in[0];
    const float* w = (const float*)d_in[1];
    float* out = (float*)d_out;

    char* ws = (char*)d_ws;
    float* bsq = (float*)ws;                               // 4 KB
    float* wmaxp = (float*)(ws + 4096);                    // 16 B
    unsigned short* wbf = (unsigned short*)(ws + 8192);    // 128 KB

    prep_w<<<1, 1024, 0, stream>>>(w, bsq, wbf, wmaxp);
    vq_scan<<<NBLK, BLKT, 0, stream>>>(h, w, wbf, bsq, wmaxp, out);
}